// Round 6
// baseline (1793.597 us; speedup 1.0000x reference)
//
#include <hip/hip_runtime.h>

// Problem constants
#define B_    128
#define HIDD  512
#define NCLS  7000
#define NPAD  7040
#define LSEQ  40
#define MROWS 5120   // LSEQ * B_
#define TT    10     // t-steps per k_feat block (40 = 4 * 10)
#define SBLK  16     // persistent scan blocks

typedef __attribute__((ext_vector_type(8))) short bf16x8;
typedef __attribute__((ext_vector_type(4))) float f32x4;

__device__ __forceinline__ unsigned short f2bf(float x) {
  union { float f; unsigned u; } v; v.f = x;
  unsigned r = v.u + 0x7fffu + ((v.u >> 16) & 1u);   // RNE
  return (unsigned short)(r >> 16);
}
__device__ __forceinline__ float bf2f(unsigned short h) {
  union { unsigned u; float f; } v; v.u = ((unsigned)h) << 16;
  return v.f;
}
__device__ __forceinline__ float sigm(float x) { return 1.f / (1.f + __expf(-x)); }
__device__ __forceinline__ float tanh_f(float x) {
  float e = __expf(2.f * x);
  return 1.f - 2.f / (e + 1.f);
}
__device__ __forceinline__ float rcp_f(float x) { return __builtin_amdgcn_rcpf(x); }

// ---------------- fused preprocessing: all conversions in ONE launch ----------------
// block ranges: [0,1024) cvtp W_ih (+bsum) | [1024,2048) cvtp W_hh | [2048,2304) cvt hemw
// [2304,18688) expcvt x_em | [18688,25728) linpad | [25728,28288) xts.  Also zeroes cnt.
__global__ __launch_bounds__(256) void k_pre(const float* __restrict__ W_ih,
                                             const float* __restrict__ W_hh,
                                             unsigned short* __restrict__ wihp,
                                             unsigned short* __restrict__ whhp,
                                             const float* __restrict__ b_ih,
                                             const float* __restrict__ b_hh,
                                             float* __restrict__ bsum,
                                             const float* __restrict__ hem_w,
                                             unsigned short* __restrict__ hemw,
                                             const float* __restrict__ x_em,
                                             unsigned short* __restrict__ xem,
                                             const float* __restrict__ lin_w,
                                             unsigned short* __restrict__ linw,
                                             const float* __restrict__ hidden_en,
                                             const float* __restrict__ embed_w,
                                             const int* __restrict__ target,
                                             unsigned short* __restrict__ xts,
                                             int* __restrict__ cnt) {
  const int bid = blockIdx.x, tid = threadIdx.x;
  if (bid == 0 && tid == 0)
    __hip_atomic_store(cnt, 0, __ATOMIC_RELAXED, __HIP_MEMORY_SCOPE_AGENT);
  if (bid < 2048) {
    // gate-permuted bf16 convert of a [2048][512] matrix.
    // dst row n <-> (gate g=(n>>4)&3, col j=(n>>6)*16+(n&15)); src row = g*512+j.
    const bool isA = bid < 1024;
    const float* src = isA ? W_ih : W_hh;
    unsigned short* dst = isA ? wihp : whhp;
    int i = (isA ? bid : bid - 1024) * 256 + tid;   // over 2048*512/4
    int e = i * 4;
    int n = e >> 9, col = e & 511;
    int srow = ((n >> 4) & 3) * 512 + (n >> 6) * 16 + (n & 15);
    float4 v = *(const float4*)(src + (size_t)srow * 512 + col);
    ushort4 o; o.x = f2bf(v.x); o.y = f2bf(v.y); o.z = f2bf(v.z); o.w = f2bf(v.w);
    ((ushort4*)dst)[i] = o;
    if (isA && col == 0) bsum[n] = b_ih[srow] + b_hh[srow];
  } else if (bid < 2304) {
    int i = (bid - 2048) * 256 + tid;               // over 512*512/4
    float4 v = ((const float4*)hem_w)[i];
    ushort4 o; o.x = f2bf(v.x); o.y = f2bf(v.y); o.z = f2bf(v.z); o.w = f2bf(v.w);
    ((ushort4*)hemw)[i] = o;
  } else if (bid < 18688) {
    int i = (bid - 2304) * 256 + tid;               // over 128*512*256/4
    float4 v = ((const float4*)x_em)[i];
    ushort4 o;
    o.x = f2bf(__expf(2.f * v.x)); o.y = f2bf(__expf(2.f * v.y));
    o.z = f2bf(__expf(2.f * v.z)); o.w = f2bf(__expf(2.f * v.w));
    ((ushort4*)xem)[i] = o;
  } else if (bid < 25728) {
    int i = (bid - 18688) * 256 + tid;              // over 7040*1024/4
    int e = i * 4;
    int row = e >> 10;
    ushort4 o;
    if (row < NCLS) {
      float4 v = *(const float4*)(lin_w + (size_t)row * 1024 + (e & 1023));
      o.x = f2bf(v.x); o.y = f2bf(v.y); o.z = f2bf(v.z); o.w = f2bf(v.w);
    } else { o.x = 0; o.y = 0; o.z = 0; o.w = 0; }
    ((ushort4*)linw)[i] = o;
  } else {
    int i = (bid - 25728) * 256 + tid;              // over 5120*512/4
    int e = i * 4;
    int r = e >> 9, col = e & 511;
    int l = r >> 7, b = r & 127;
    const float* src;
    if (l == 0) src = hidden_en + b * 512 + col;
    else        src = embed_w + (size_t)target[b * LSEQ + (l - 1)] * 512 + col;
    float4 v = *(const float4*)src;
    ushort4 o; o.x = f2bf(v.x); o.y = f2bf(v.y); o.z = f2bf(v.z); o.w = f2bf(v.w);
    ((ushort4*)xts)[i] = o;
  }
}

// ---------------- bf16 MFMA GEMM: C[M][N] = A[M][K] @ Bw[N][K]^T + bias ----------------
// (round-4 proven staging path)
template <int MODE>
__global__ __launch_bounds__(256) void k_gemm(const unsigned short* __restrict__ A, int lda,
                                              const unsigned short* __restrict__ Bw, int ldb,
                                              const float* __restrict__ bias,
                                              void* __restrict__ outp, int ldc, int K) {
  __shared__ __align__(16) unsigned short As[128 * 32];
  __shared__ __align__(16) unsigned short Bs[128 * 32];
  const int tid = threadIdx.x;
  const int lane = tid & 63, wid = tid >> 6;
  const int wm = wid >> 1, wn = wid & 1;
  const int quad = lane >> 4, l16 = lane & 15;
  const int m0 = blockIdx.x * 128, n0 = blockIdx.y * 128;
  f32x4 acc[4][4];
#pragma unroll
  for (int i = 0; i < 4; i++)
#pragma unroll
    for (int j = 0; j < 4; j++) acc[i][j] = (f32x4){0.f, 0.f, 0.f, 0.f};

  const int r0 = tid >> 2, kq0 = (tid & 3) * 8;
  for (int k0 = 0; k0 < K; k0 += 32) {
#pragma unroll
    for (int s = 0; s < 2; s++) {
      int row = r0 + s * 64;
      *(bf16x8*)(As + row * 32 + kq0) = *(const bf16x8*)(A + (size_t)(m0 + row) * lda + k0 + kq0);
      *(bf16x8*)(Bs + row * 32 + kq0) = *(const bf16x8*)(Bw + (size_t)(n0 + row) * ldb + k0 + kq0);
    }
    __syncthreads();
    bf16x8 af[4], bfr[4];
#pragma unroll
    for (int i = 0; i < 4; i++)
      af[i] = *(const bf16x8*)(As + (wm * 64 + i * 16 + l16) * 32 + quad * 8);
#pragma unroll
    for (int j = 0; j < 4; j++)
      bfr[j] = *(const bf16x8*)(Bs + (wn * 64 + j * 16 + l16) * 32 + quad * 8);
#pragma unroll
    for (int i = 0; i < 4; i++)
#pragma unroll
      for (int j = 0; j < 4; j++)
        acc[i][j] = __builtin_amdgcn_mfma_f32_16x16x32_bf16(af[i], bfr[j], acc[i][j], 0, 0, 0);
    __syncthreads();
  }
  // epilogue: D layout col=lane&15, row=quad*4+r  [verified m89/m91]
#pragma unroll
  for (int i = 0; i < 4; i++) {
    int mbase = m0 + wm * 64 + i * 16 + quad * 4;
#pragma unroll
    for (int j = 0; j < 4; j++) {
      int n = n0 + wn * 64 + j * 16 + l16;
#pragma unroll
      for (int r = 0; r < 4; r++) {
        float v = acc[i][j][r];
        int m = mbase + r;
        if (MODE == 0) {
          ((unsigned short*)outp)[(size_t)m * ldc + n] = f2bf(v + bias[n]);
        } else if (MODE == 3) {
          ((float*)outp)[(size_t)m * ldc + n] = __expf(2.f * (v + bias[n]));
        } else {
          if (n < NCLS) {
            int t = m >> 7, b = m & 127;
            ((float*)outp)[((size_t)(b * LSEQ + t)) * NCLS + n] = v + bias[n];
          }
        }
      }
    }
  }
}

// ---------------- fallback: one LSTM timestep (verified round-4 path) ----------------
__global__ __launch_bounds__(256) void k_step(const unsigned short* __restrict__ h_prev,
                                              unsigned short* __restrict__ h_new,
                                              float* __restrict__ c_buf,
                                              const unsigned short* __restrict__ xg,
                                              const unsigned short* __restrict__ whhp,
                                              unsigned short* __restrict__ hatt, int t) {
  __shared__ __align__(16) unsigned short As[128 * 32];
  __shared__ __align__(16) unsigned short Bs[128 * 32];
  const int tid = threadIdx.x;
  const int lane = tid & 63, wid = tid >> 6;
  const int wm = wid >> 1, wn = wid & 1;
  const int quad = lane >> 4, l16 = lane & 15;
  const int n0 = blockIdx.x * 128;
  f32x4 acc[4][4];
#pragma unroll
  for (int i = 0; i < 4; i++)
#pragma unroll
    for (int j = 0; j < 4; j++) acc[i][j] = (f32x4){0.f, 0.f, 0.f, 0.f};

  if (t > 0) {
    const int r0 = tid >> 2, kq0 = (tid & 3) * 8;
    for (int k0 = 0; k0 < 512; k0 += 32) {
#pragma unroll
      for (int s = 0; s < 2; s++) {
        int row = r0 + s * 64;
        *(bf16x8*)(As + row * 32 + kq0) = *(const bf16x8*)(h_prev + (size_t)row * 512 + k0 + kq0);
        *(bf16x8*)(Bs + row * 32 + kq0) = *(const bf16x8*)(whhp + (size_t)(n0 + row) * 512 + k0 + kq0);
      }
      __syncthreads();
      bf16x8 af[4], bfr[4];
#pragma unroll
      for (int i = 0; i < 4; i++)
        af[i] = *(const bf16x8*)(As + (wm * 64 + i * 16 + l16) * 32 + quad * 8);
#pragma unroll
      for (int j = 0; j < 4; j++)
        bfr[j] = *(const bf16x8*)(Bs + (wn * 64 + j * 16 + l16) * 32 + quad * 8);
#pragma unroll
      for (int i = 0; i < 4; i++)
#pragma unroll
        for (int j = 0; j < 4; j++)
          acc[i][j] = __builtin_amdgcn_mfma_f32_16x16x32_bf16(af[i], bfr[j], acc[i][j], 0, 0, 0);
      __syncthreads();
    }
  }
  const int jcol = ((n0 >> 6) + wn) * 16 + l16;
#pragma unroll
  for (int i = 0; i < 4; i++) {
    int mbase = wm * 64 + i * 16 + quad * 4;
#pragma unroll
    for (int r = 0; r < 4; r++) {
      int m = mbase + r;
      const unsigned short* xrow = xg + (size_t)(t * 128 + m) * 2048 + n0 + wn * 64 + l16;
      float ip = acc[i][0][r] + bf2f(xrow[0]);
      float fp = acc[i][1][r] + bf2f(xrow[16]);
      float gp = acc[i][2][r] + bf2f(xrow[32]);
      float op = acc[i][3][r] + bf2f(xrow[48]);
      float c_old = (t > 0) ? c_buf[m * 512 + jcol] : 0.f;
      float c = sigm(fp) * c_old + sigm(ip) * tanh_f(gp);
      c_buf[m * 512 + jcol] = c;
      float h = sigm(op) * tanh_f(c);
      unsigned short hb = f2bf(h);
      h_new[m * 512 + jcol] = hb;
      hatt[(size_t)(t * 128 + m) * 1024 + jcol] = hb;
    }
  }
}

// ---------------- persistent 40-step LSTM scan v4: per-ACCESS coherence, no fences ----
// Same math as k_step/k_scan3 (bit-identical). Coherence scheme:
//  - h stores: asm sc0 sc1 (write-through to L3, no L1/L2 allocate)
//  - h loads: __builtin_nontemporal_load (nt never allocates L1/L2 -> no stale copy can
//    ever exist -> always fresh from L3; remains a plain compiler-pipelined load)
//  - barrier: monotonic counter; publish = RELAXED add (after syncthreads' vmcnt drain);
//    poll = RELAXED fetch_add(0) RMW (coherent at L3 by construction). NO __threadfence,
//    so xg/W stay L2-hot across all 40 steps.
__global__ __launch_bounds__(256) void k_scan4(unsigned short* __restrict__ h0,
                                               unsigned short* __restrict__ h1,
                                               const unsigned short* __restrict__ xg,
                                               const unsigned short* __restrict__ whhp,
                                               unsigned short* __restrict__ hatt,
                                               int* __restrict__ cnt) {
  __shared__ __align__(16) unsigned short Wl[128 * 512];   // 128 KB, XOR-swizzled
  const int tid = threadIdx.x;
  const int lane = tid & 63, wid = tid >> 6;
  const int wm = wid >> 1, wn = wid & 1;
  const int quad = lane >> 4, l16 = lane & 15;
  const int n0 = blockIdx.x * 128;

  // preload this block's W slice (reg-staged swizzle; read-only data, plain loads)
  for (int i = tid; i < 128 * 64; i += 256) {   // 128 rows x 64 chunks of 8 bf16
    int row = i >> 6, c8 = (i & 63) << 3;
    bf16x8 v = *(const bf16x8*)(whhp + (size_t)(n0 + row) * 512 + c8);
    *(bf16x8*)((char*)Wl + ((row * 1024 + c8 * 2) ^ ((row & 7) << 4))) = v;
  }
  float cst[4][4];
#pragma unroll
  for (int i = 0; i < 4; i++)
#pragma unroll
    for (int r = 0; r < 4; r++) cst[i][r] = 0.f;
  const int jcol = ((n0 >> 6) + wn) * 16 + l16;
  __syncthreads();

  for (int t = 0; t < LSEQ; t++) {
    f32x4 acc[4][4];
#pragma unroll
    for (int i = 0; i < 4; i++)
#pragma unroll
      for (int j = 0; j < 4; j++) acc[i][j] = (f32x4){0.f, 0.f, 0.f, 0.f};
    if (t > 0) {
      const unsigned short* hp = (t & 1) ? h0 : h1;
      const unsigned short* hb = hp + (size_t)(wm * 64 + l16) * 512 + quad * 8;
#pragma unroll 4
      for (int k0 = 0; k0 < 512; k0 += 32) {
        bf16x8 af[4], bfr[4];
#pragma unroll
        for (int i = 0; i < 4; i++)
          af[i] = __builtin_nontemporal_load(
              (const bf16x8*)(hb + (size_t)i * 16 * 512 + k0));
#pragma unroll
        for (int j = 0; j < 4; j++) {
          int rw = wn * 64 + j * 16 + l16;
          bfr[j] = *(const bf16x8*)((const char*)Wl +
                    ((rw * 1024 + (k0 + quad * 8) * 2) ^ ((rw & 7) << 4)));
        }
#pragma unroll
        for (int i = 0; i < 4; i++)
#pragma unroll
          for (int j = 0; j < 4; j++)
            acc[i][j] = __builtin_amdgcn_mfma_f32_16x16x32_bf16(af[i], bfr[j], acc[i][j], 0, 0, 0);
      }
    }
    // LSTM epilogue (identical math/order to k_step)
    unsigned short* hn = (t & 1) ? h1 : h0;
    const unsigned short* xq = xg + (size_t)(t * 128) * 2048 + n0 + wn * 64 + l16;
#pragma unroll
    for (int i = 0; i < 4; i++) {
#pragma unroll
      for (int r = 0; r < 4; r++) {
        int m = wm * 64 + i * 16 + quad * 4 + r;
        const unsigned short* xrow = xq + (size_t)m * 2048;
        float ip = acc[i][0][r] + bf2f(xrow[0]);
        float fp = acc[i][1][r] + bf2f(xrow[16]);
        float gp = acc[i][2][r] + bf2f(xrow[32]);
        float op = acc[i][3][r] + bf2f(xrow[48]);
        float c = sigm(fp) * cst[i][r] + sigm(ip) * tanh_f(gp);
        cst[i][r] = c;
        float h = sigm(op) * tanh_f(c);
        unsigned short hbv = f2bf(h);
        // h: write-through to L3 (sc0 sc1) so nt readers always see it
        unsigned short* hdst = hn + m * 512 + jcol;
        asm volatile("global_store_short %0, %1, off sc0 sc1"
                     :: "v"(hdst), "v"((unsigned)hbv) : "memory");
        hatt[(size_t)(t * 128 + m) * 1024 + jcol] = hbv;   // consumed post-kernel
      }
    }
    if (t < LSEQ - 1) {
      __syncthreads();   // each wave drains vmcnt(0) before barrier -> sc1 stores at L3
      if (tid == 0) {
        __hip_atomic_fetch_add(cnt, 1, __ATOMIC_RELAXED, __HIP_MEMORY_SCOPE_AGENT);
        const int tgt = SBLK * (t + 1);    // monotonic: never resets mid-launch
        while (__hip_atomic_fetch_add(cnt, 0, __ATOMIC_RELAXED,
                                      __HIP_MEMORY_SCOPE_AGENT) < tgt)
          __builtin_amdgcn_s_sleep(4);
      }
      __syncthreads();
    }
  }
}

// ---------------- attention scores via exp-factorized tanh ----------------
__global__ __launch_bounds__(256) void k_feat(const float* __restrict__ Eh,
                                              const unsigned short* __restrict__ Ex,
                                              const float* __restrict__ attw_w,
                                              float* __restrict__ s_all) {
  __shared__ float EhL[TT][512];
  __shared__ float wL[512];
  const int tid = threadIdx.x;
  const int tg = blockIdx.x >> 7, b = blockIdx.x & 127;
  const int t0 = tg * TT;
  for (int i = tid * 4; i < TT * 512; i += 1024) {
    int t = i >> 9, c = i & 511;
    *(float4*)&EhL[t][c] = *(const float4*)&Eh[((size_t)(t0 + t) * 128 + b) * 512 + c];
  }
  if (tid < 128) *(float4*)&wL[tid * 4] = *(const float4*)&attw_w[tid * 4];
  __syncthreads();
  const int p = tid;
  const unsigned short* xp = Ex + (size_t)b * 512 * 256 + p;
  float acc[TT];
#pragma unroll
  for (int t = 0; t < TT; t++) acc[t] = 0.f;
  for (int c0 = 0; c0 < 512; c0 += 4) {
    float ex0 = bf2f(xp[(size_t)(c0 + 0) * 256]);
    float ex1 = bf2f(xp[(size_t)(c0 + 1) * 256]);
    float ex2 = bf2f(xp[(size_t)(c0 + 2) * 256]);
    float ex3 = bf2f(xp[(size_t)(c0 + 3) * 256]);
    float4 wv = *(const float4*)&wL[c0];
#pragma unroll
    for (int t = 0; t < TT; t++) {
      float4 eh = *(const float4*)&EhL[t][c0];
      acc[t] = __builtin_fmaf(wv.x, rcp_f(__builtin_fmaf(ex0, eh.x, 1.f)), acc[t]);
      acc[t] = __builtin_fmaf(wv.y, rcp_f(__builtin_fmaf(ex1, eh.y, 1.f)), acc[t]);
      acc[t] = __builtin_fmaf(wv.z, rcp_f(__builtin_fmaf(ex2, eh.z, 1.f)), acc[t]);
      acc[t] = __builtin_fmaf(wv.w, rcp_f(__builtin_fmaf(ex3, eh.w, 1.f)), acc[t]);
    }
  }
#pragma unroll
  for (int t = 0; t < TT; t++)
    s_all[((size_t)(t0 + t) * 128 + b) * 256 + p] = -2.f * acc[t];
}

// ---------------- softmax over p (per t,b) + att[t,b,d] = sum_p alpha * att_x_em[b,p,d] ----------------
__global__ __launch_bounds__(256) void k_att(const float* __restrict__ s_all,
                                             const float* __restrict__ atx,
                                             unsigned short* __restrict__ hatt) {
  __shared__ float sL[40][257];
  __shared__ float zinv[40];
  const int tid = threadIdx.x;
  const int b = blockIdx.x >> 1, dh = blockIdx.x & 1;
  for (int i = tid; i < 40 * 256; i += 256) {
    int t = i >> 8, p = i & 255;
    sL[t][p] = s_all[((size_t)t * 128 + b) * 256 + p];
  }
  __syncthreads();
  if (tid < 40) {
    int t = tid;
    float mx = -1e30f;
    for (int p = 0; p < 256; p++) mx = fmaxf(mx, sL[t][p]);
    float z = 0.f;
    for (int p = 0; p < 256; p++) { float e = __expf(sL[t][p] - mx); sL[t][p] = e; z += e; }
    zinv[t] = 1.f / z;
  }
  __syncthreads();
  float acc[40];
#pragma unroll
  for (int t = 0; t < 40; t++) acc[t] = 0.f;
  const int d = dh * 256 + tid;
  const float* ap = atx + (size_t)b * 256 * 512 + d;
  for (int p = 0; p < 256; p++) {
    float av = ap[(size_t)p * 512];
#pragma unroll
    for (int t = 0; t < 40; t++) acc[t] += sL[t][p] * av;
  }
#pragma unroll
  for (int t = 0; t < 40; t++) {
    float v = acc[t] * zinv[t];
    hatt[((size_t)t * 128 + b) * 1024 + 512 + d] = f2bf(v);
  }
}

// ---------------- in-place log_softmax over rows of 7000 in d_out ----------------
__global__ __launch_bounds__(256) void k_lsm(float* __restrict__ out) {
  __shared__ float buf[7000];
  __shared__ float red[256];
  const int tid = threadIdx.x;
  float* pr = out + (size_t)blockIdx.x * NCLS;
  for (int i = tid * 4; i < NCLS; i += 1024)
    *(float4*)&buf[i] = *(const float4*)&pr[i];
  __syncthreads();
  float mx = -1e30f;
  for (int i = tid; i < NCLS; i += 256) mx = fmaxf(mx, buf[i]);
  red[tid] = mx; __syncthreads();
  for (int s = 128; s > 0; s >>= 1) { if (tid < s) red[tid] = fmaxf(red[tid], red[tid + s]); __syncthreads(); }
  mx = red[0]; __syncthreads();
  float sum = 0.f;
  for (int i = tid; i < NCLS; i += 256) sum += __expf(buf[i] - mx);
  red[tid] = sum; __syncthreads();
  for (int s = 128; s > 0; s >>= 1) { if (tid < s) red[tid] += red[tid + s]; __syncthreads(); }
  float lse = mx + __logf(red[0]);
  for (int i = tid * 4; i < NCLS; i += 1024) {
    float4 v = *(const float4*)&buf[i];
    v.x -= lse; v.y -= lse; v.z -= lse; v.w -= lse;
    *(float4*)&pr[i] = v;
  }
}

extern "C" void kernel_launch(void* const* d_in, const int* in_sizes, int n_in,
                              void* d_out, int out_size, void* d_ws, size_t ws_size,
                              hipStream_t stream) {
  const float* hidden_en = (const float*)d_in[0];
  const float* x_em      = (const float*)d_in[1];
  const float* att_x     = (const float*)d_in[2];
  const int*   target    = (const int*)d_in[3];
  const float* embed_w   = (const float*)d_in[6];
  const float* W_ih      = (const float*)d_in[7];
  const float* W_hh      = (const float*)d_in[8];
  const float* b_ih      = (const float*)d_in[9];
  const float* b_hh      = (const float*)d_in[10];
  const float* hem_w     = (const float*)d_in[11];
  const float* hem_b     = (const float*)d_in[12];
  const float* attw_w    = (const float*)d_in[13];
  const float* lin_w     = (const float*)d_in[15];
  const float* lin_b     = (const float*)d_in[16];
  float* out = (float*)d_out;
  (void)in_sizes; (void)n_in; (void)out_size; (void)ws_size;

  char* w = (char*)d_ws;
  size_t off = 0;
  auto alloc = [&](size_t bytes) { char* p = w + off; off = (off + bytes + 255) & ~(size_t)255; return p; };
  unsigned short* xts  = (unsigned short*)alloc((size_t)MROWS * 512 * 2);
  unsigned short* wihp = (unsigned short*)alloc((size_t)2048 * 512 * 2);  // W_ih bf16, gate-permuted rows
  unsigned short* whhp = (unsigned short*)alloc((size_t)2048 * 512 * 2);  // W_hh bf16, gate-permuted rows
  unsigned short* xg   = (unsigned short*)alloc((size_t)MROWS * 2048 * 2); // permuted cols, b_ih+b_hh baked in
  unsigned short* hemw = (unsigned short*)alloc((size_t)512 * 512 * 2);
  unsigned short* linw = (unsigned short*)alloc((size_t)NPAD * 1024 * 2);
  unsigned short* xem  = (unsigned short*)alloc((size_t)128 * 512 * 256 * 2);  // Ex = exp(2*x_em) bf16
  unsigned short* hatt = (unsigned short*)alloc((size_t)MROWS * 1024 * 2);
  unsigned short* h0   = (unsigned short*)alloc((size_t)128 * 512 * 2);
  unsigned short* h1   = (unsigned short*)alloc((size_t)128 * 512 * 2);
  float* cb      = (float*)alloc((size_t)128 * 512 * 4);
  float* bsum    = (float*)alloc((size_t)2048 * 4);          // b_ih + b_hh, permuted
  float* eh_all  = (float*)alloc((size_t)MROWS * 512 * 4);   // Eh = exp(2*hem)
  float* s_all   = (float*)alloc((size_t)MROWS * 256 * 4);
  int*   cnt     = (int*)alloc(256);                         // scan barrier counter

  // --- all preprocessing in ONE launch (cnt zeroed inside, stream-ordered) ---
  k_pre<<<28288, 256, 0, stream>>>(W_ih, W_hh, wihp, whhp, b_ih, b_hh, bsum,
                                   hem_w, hemw, x_em, xem, lin_w, linw,
                                   hidden_en, embed_w, target, xts, cnt);
  // xg_all = xts @ W_ih_perm^T + (b_ih + b_hh)  (bf16 out, permuted cols)
  k_gemm<0><<<dim3(40, 16), 256, 0, stream>>>(xts, 512, wihp, 512, bsum, xg, 2048, 512);

  // --- fused sequential LSTM scan: ONE persistent cooperative launch ---
  {
    void* args[] = { (void*)&h0, (void*)&h1, (void*)&xg, (void*)&whhp, (void*)&hatt, (void*)&cnt };
    hipError_t ce = hipLaunchCooperativeKernel(k_scan4, dim3(SBLK), dim3(256), args, 0u, stream);
    if (ce != hipSuccess) {
      // fallback: verified round-4 path (40 launches)
      for (int t = 0; t < LSEQ; t++) {
        const unsigned short* hp = (t & 1) ? h0 : h1;
        unsigned short* hn = (t & 1) ? h1 : h0;
        k_step<<<16, 256, 0, stream>>>(hp, hn, cb, xg, whhp, hatt, t);
      }
    }
  }

  // --- batched attention over all 40 steps ---
  // Eh = exp(2*(h@hem_w^T + hem_b)) fused into GEMM epilogue (MODE 3)
  k_gemm<3><<<dim3(40, 4), 256, 0, stream>>>(hatt, 1024, hemw, 512, hem_b, eh_all, 512, 512);
  k_feat<<<512, 256, 0, stream>>>(eh_all, xem, attw_w, s_all);
  k_att<<<256, 256, 0, stream>>>(s_all, att_x, hatt);

  // --- logits + log_softmax ---
  k_gemm<2><<<dim3(40, 55), 256, 0, stream>>>(hatt, 1024, linw, 1024, lin_b, out, NCLS, 1024);
  k_lsm<<<MROWS, 256, 0, stream>>>(out);
}

// Round 7
// 1378.566 us; speedup vs baseline: 1.3011x; 1.3011x over previous
//
#include <hip/hip_runtime.h>

// Problem constants
#define B_    128
#define HIDD  512
#define NCLS  7000
#define NPAD  7040
#define LSEQ  40
#define MROWS 5120   // LSEQ * B_
#define TT    10     // t-steps per k_feat block (40 = 4 * 10)
#define SBLK  16     // persistent scan blocks

typedef __attribute__((ext_vector_type(8))) short bf16x8;
typedef __attribute__((ext_vector_type(4))) float f32x4;
typedef __attribute__((ext_vector_type(4))) unsigned int u32x4;

__device__ __forceinline__ unsigned short f2bf(float x) {
  union { float f; unsigned u; } v; v.f = x;
  unsigned r = v.u + 0x7fffu + ((v.u >> 16) & 1u);   // RNE
  return (unsigned short)(r >> 16);
}
__device__ __forceinline__ float bf2f(unsigned short h) {
  union { unsigned u; float f; } v; v.u = ((unsigned)h) << 16;
  return v.f;
}
__device__ __forceinline__ float sigm(float x) { return 1.f / (1.f + __expf(-x)); }
__device__ __forceinline__ float tanh_f(float x) {
  float e = __expf(2.f * x);
  return 1.f - 2.f / (e + 1.f);
}
__device__ __forceinline__ float rcp_f(float x) { return __builtin_amdgcn_rcpf(x); }

// ---------------- fused preprocessing: all conversions in ONE launch ----------------
// block ranges: [0,1024) cvtp W_ih (+bsum) | [1024,2048) cvtp W_hh | [2048,2304) cvt hemw
// [2304,18688) expcvt x_em | [18688,25728) linpad | [25728,28288) xts.  Also zeroes cnt.
// Gate permutation (ROUND-3 verified): dst row n = [w:4][nt:3][hi2:2][g:2] <->
// src row = g*512 + (w*32 + nt*4 + hi2).  With mfma(W,h) swapped operands, thread
// (quad,l16) of n-tile gets acc.xyzw = gates (i,f,g,o) of j = w*32+nt*4+quad, m=l16.
__global__ __launch_bounds__(256) void k_pre(const float* __restrict__ W_ih,
                                             const float* __restrict__ W_hh,
                                             unsigned short* __restrict__ wihp,
                                             unsigned short* __restrict__ whhp,
                                             const float* __restrict__ b_ih,
                                             const float* __restrict__ b_hh,
                                             float* __restrict__ bsum,
                                             const float* __restrict__ hem_w,
                                             unsigned short* __restrict__ hemw,
                                             const float* __restrict__ x_em,
                                             unsigned short* __restrict__ xem,
                                             const float* __restrict__ lin_w,
                                             unsigned short* __restrict__ linw,
                                             const float* __restrict__ hidden_en,
                                             const float* __restrict__ embed_w,
                                             const int* __restrict__ target,
                                             unsigned short* __restrict__ xts,
                                             int* __restrict__ cnt) {
  const int bid = blockIdx.x, tid = threadIdx.x;
  if (bid == 0 && tid == 0)
    __hip_atomic_store(cnt, 0, __ATOMIC_RELAXED, __HIP_MEMORY_SCOPE_AGENT);
  if (bid < 2048) {
    const bool isA = bid < 1024;
    const float* src = isA ? W_ih : W_hh;
    unsigned short* dst = isA ? wihp : whhp;
    int i = (isA ? bid : bid - 1024) * 256 + tid;   // over 2048*512/4
    int e = i * 4;
    int n = e >> 9, col = e & 511;
    int srow = (n & 3) * 512 + (n >> 7) * 32 + ((n >> 4) & 7) * 4 + ((n >> 2) & 3);
    float4 v = *(const float4*)(src + (size_t)srow * 512 + col);
    ushort4 o; o.x = f2bf(v.x); o.y = f2bf(v.y); o.z = f2bf(v.z); o.w = f2bf(v.w);
    ((ushort4*)dst)[i] = o;
    if (isA && col == 0) bsum[n] = b_ih[srow] + b_hh[srow];
  } else if (bid < 2304) {
    int i = (bid - 2048) * 256 + tid;               // over 512*512/4
    float4 v = ((const float4*)hem_w)[i];
    ushort4 o; o.x = f2bf(v.x); o.y = f2bf(v.y); o.z = f2bf(v.z); o.w = f2bf(v.w);
    ((ushort4*)hemw)[i] = o;
  } else if (bid < 18688) {
    int i = (bid - 2304) * 256 + tid;               // over 128*512*256/4
    float4 v = ((const float4*)x_em)[i];
    ushort4 o;
    o.x = f2bf(__expf(2.f * v.x)); o.y = f2bf(__expf(2.f * v.y));
    o.z = f2bf(__expf(2.f * v.z)); o.w = f2bf(__expf(2.f * v.w));
    ((ushort4*)xem)[i] = o;
  } else if (bid < 25728) {
    int i = (bid - 18688) * 256 + tid;              // over 7040*1024/4
    int e = i * 4;
    int row = e >> 10;
    ushort4 o;
    if (row < NCLS) {
      float4 v = *(const float4*)(lin_w + (size_t)row * 1024 + (e & 1023));
      o.x = f2bf(v.x); o.y = f2bf(v.y); o.z = f2bf(v.z); o.w = f2bf(v.w);
    } else { o.x = 0; o.y = 0; o.z = 0; o.w = 0; }
    ((ushort4*)linw)[i] = o;
  } else {
    int i = (bid - 25728) * 256 + tid;              // over 5120*512/4
    int e = i * 4;
    int r = e >> 9, col = e & 511;
    int l = r >> 7, b = r & 127;
    const float* src;
    if (l == 0) src = hidden_en + b * 512 + col;
    else        src = embed_w + (size_t)target[b * LSEQ + (l - 1)] * 512 + col;
    float4 v = *(const float4*)src;
    ushort4 o; o.x = f2bf(v.x); o.y = f2bf(v.y); o.z = f2bf(v.z); o.w = f2bf(v.w);
    ((ushort4*)xts)[i] = o;
  }
}

// ---------------- bf16 MFMA GEMM: C[M][N] = A[M][K] @ Bw[N][K]^T + bias ----------------
// (round-4 proven staging path)
template <int MODE>
__global__ __launch_bounds__(256) void k_gemm(const unsigned short* __restrict__ A, int lda,
                                              const unsigned short* __restrict__ Bw, int ldb,
                                              const float* __restrict__ bias,
                                              void* __restrict__ outp, int ldc, int K) {
  __shared__ __align__(16) unsigned short As[128 * 32];
  __shared__ __align__(16) unsigned short Bs[128 * 32];
  const int tid = threadIdx.x;
  const int lane = tid & 63, wid = tid >> 6;
  const int wm = wid >> 1, wn = wid & 1;
  const int quad = lane >> 4, l16 = lane & 15;
  const int m0 = blockIdx.x * 128, n0 = blockIdx.y * 128;
  f32x4 acc[4][4];
#pragma unroll
  for (int i = 0; i < 4; i++)
#pragma unroll
    for (int j = 0; j < 4; j++) acc[i][j] = (f32x4){0.f, 0.f, 0.f, 0.f};

  const int r0 = tid >> 2, kq0 = (tid & 3) * 8;
  for (int k0 = 0; k0 < K; k0 += 32) {
#pragma unroll
    for (int s = 0; s < 2; s++) {
      int row = r0 + s * 64;
      *(bf16x8*)(As + row * 32 + kq0) = *(const bf16x8*)(A + (size_t)(m0 + row) * lda + k0 + kq0);
      *(bf16x8*)(Bs + row * 32 + kq0) = *(const bf16x8*)(Bw + (size_t)(n0 + row) * ldb + k0 + kq0);
    }
    __syncthreads();
    bf16x8 af[4], bfr[4];
#pragma unroll
    for (int i = 0; i < 4; i++)
      af[i] = *(const bf16x8*)(As + (wm * 64 + i * 16 + l16) * 32 + quad * 8);
#pragma unroll
    for (int j = 0; j < 4; j++)
      bfr[j] = *(const bf16x8*)(Bs + (wn * 64 + j * 16 + l16) * 32 + quad * 8);
#pragma unroll
    for (int i = 0; i < 4; i++)
#pragma unroll
      for (int j = 0; j < 4; j++)
        acc[i][j] = __builtin_amdgcn_mfma_f32_16x16x32_bf16(af[i], bfr[j], acc[i][j], 0, 0, 0);
    __syncthreads();
  }
  // epilogue: D layout col=lane&15, row=quad*4+r  [verified m89/m91]
#pragma unroll
  for (int i = 0; i < 4; i++) {
    int mbase = m0 + wm * 64 + i * 16 + quad * 4;
#pragma unroll
    for (int j = 0; j < 4; j++) {
      int n = n0 + wn * 64 + j * 16 + l16;
#pragma unroll
      for (int r = 0; r < 4; r++) {
        float v = acc[i][j][r];
        int m = mbase + r;
        if (MODE == 0) {
          ((unsigned short*)outp)[(size_t)m * ldc + n] = f2bf(v + bias[n]);
        } else if (MODE == 3) {
          ((float*)outp)[(size_t)m * ldc + n] = __expf(2.f * (v + bias[n]));
        } else {
          if (n < NCLS) {
            int t = m >> 7, b = m & 127;
            ((float*)outp)[((size_t)(b * LSEQ + t)) * NCLS + n] = v + bias[n];
          }
        }
      }
    }
  }
}

// ---------------- persistent LSTM scan v5: occupancy-first, swapped-operand MFMA ----
// 16 blocks x 1024 threads (16 waves = 4/SIMD for latency hiding). Per block: N-slice of
// 128 gate-rows (32 j's), all M=128. Per step:
//  - h (128 KB) staged global->LDS with sc0 sc1 coherent loads (8/thread, full MLP),
//    XOR-swizzled; read by all 16 waves (8x reuse)
//  - W slice streamed from L2 (read-only -> plain loads, stays hot all 40 steps)
//  - mfma(W_frag, h_frag): D[n][m]; with the round-3 gate permutation, thread (quad,l16)
//    of wave (wm,wn) holds acc[i].xyzw = (i,f,g,o) of (m = wm*64+i*16+l16,
//    j = blk*32+wn*4+quad) -> register-local LSTM update, zero shuffles  [R3-verified]
//  - h stores: sc0 sc1 write-through; barrier: monotonic relaxed-RMW poll [R6-verified
//    coherence scheme]; c-state in registers
// t0/t1: cooperative path runs (0,40) with inter-step barrier; fallback = 40 single-step
// launches of this same kernel (barrier skipped when t == t1-1).
__global__ __launch_bounds__(1024) void k_scan5(unsigned short* __restrict__ h0,
                                                unsigned short* __restrict__ h1,
                                                const unsigned short* __restrict__ xg,
                                                const unsigned short* __restrict__ whhp,
                                                unsigned short* __restrict__ hatt,
                                                int* __restrict__ cnt, int t0, int t1) {
  __shared__ __align__(16) unsigned short Hl[128 * 512];   // 128 KB, XOR-swizzled
  const int tid = threadIdx.x;
  const int lane = tid & 63, w = tid >> 6;
  const int wm = w >> 3, wn = w & 7;            // M-half (64 rows), N-tile (16 gate-rows)
  const int quad = lane >> 4, l16 = lane & 15;
  const int blk = blockIdx.x;                   // N-slice: gate-rows [blk*128, +128)
  const int jcol = blk * 32 + wn * 4 + quad;    // this thread's j
  const unsigned short* wrow = whhp + (size_t)(blk * 128 + wn * 16 + l16) * 512;

  float cst[4];
#pragma unroll
  for (int i = 0; i < 4; i++) cst[i] = 0.f;

  for (int t = t0; t < t1; t++) {
    f32x4 acc[4];
#pragma unroll
    for (int i = 0; i < 4; i++) acc[i] = (f32x4){0.f, 0.f, 0.f, 0.f};
    if (t > 0) {
      // ---- stage h_{t-1} -> LDS (coherent loads, all issued before one waitcnt) ----
      const unsigned short* hp = (t & 1) ? h0 : h1;
      u32x4 stg[8];
#pragma unroll
      for (int s = 0; s < 8; s++) {
        int idx = tid + s * 1024;
        int row = idx >> 6, ch = idx & 63;      // wave reads 1024B of one row: coalesced
        const unsigned short* src = hp + (size_t)row * 512 + ch * 8;
        asm volatile("global_load_dwordx4 %0, %1, off sc0 sc1"
                     : "=v"(stg[s]) : "v"(src));
      }
      asm volatile("s_waitcnt vmcnt(0)" ::: "memory");
#pragma unroll
      for (int s = 0; s < 8; s++) {
        int idx = tid + s * 1024;
        int row = idx >> 6, ch = idx & 63;
        *(u32x4*)((char*)Hl + ((row * 1024 + ch * 16) ^ ((row & 7) << 4))) = stg[s];
      }
      __syncthreads();
      // ---- K-loop: acc[i] (D[n][m]) over K=512; W from L2, h from LDS ----
#pragma unroll
      for (int k0 = 0; k0 < 512; k0 += 32) {
        bf16x8 af = *(const bf16x8*)(wrow + k0 + quad * 8);   // A-frag: W row
#pragma unroll
        for (int i = 0; i < 4; i++) {
          int m = wm * 64 + i * 16 + l16;                     // B-frag: h[m][k0+quad*8..]
          bf16x8 bf = *(const bf16x8*)((const char*)Hl +
                       (((m * 512 + k0 + quad * 8) * 2) ^ ((m & 7) << 4)));
          acc[i] = __builtin_amdgcn_mfma_f32_16x16x32_bf16(af, bf, acc[i], 0, 0, 0);
        }
      }
    }
    // ---- LSTM epilogue: acc[i].xyzw = (i,f,g,o) pre-activations of (m, jcol) ----
    unsigned short* hn = (t & 1) ? h1 : h0;
#pragma unroll
    for (int i = 0; i < 4; i++) {
      int m = wm * 64 + i * 16 + l16;
      const unsigned short* xp = xg + (size_t)(t * 128 + m) * 2048 +
                                 blk * 128 + wn * 16 + quad * 4;
      ushort4 xv = *(const ushort4*)xp;         // 4 gates contiguous (perm layout)
      float ip = acc[i].x + bf2f(xv.x);
      float fp = acc[i].y + bf2f(xv.y);
      float gp = acc[i].z + bf2f(xv.z);
      float op = acc[i].w + bf2f(xv.w);
      float c = sigm(fp) * cst[i] + sigm(ip) * tanh_f(gp);
      cst[i] = c;
      float h = sigm(op) * tanh_f(c);
      unsigned short hbv = f2bf(h);
      unsigned short* hdst = hn + (size_t)m * 512 + jcol;
      asm volatile("global_store_short %0, %1, off sc0 sc1"
                   :: "v"(hdst), "v"((unsigned)hbv) : "memory");
      hatt[(size_t)(t * 128 + m) * 1024 + jcol] = hbv;   // consumed post-kernel
    }
    if (t < t1 - 1) {
      __syncthreads();   // drains vmcnt per wave -> sc1 stores at L3; LDS reads done
      if (tid == 0) {
        __hip_atomic_fetch_add(cnt, 1, __ATOMIC_RELEASE, __HIP_MEMORY_SCOPE_AGENT);
        const int tgt = SBLK * (t + 1);          // monotonic: never resets mid-launch
        while (__hip_atomic_fetch_add(cnt, 0, __ATOMIC_RELAXED,
                                      __HIP_MEMORY_SCOPE_AGENT) < tgt)
          __builtin_amdgcn_s_sleep(2);
      }
      __syncthreads();
    }
  }
}

// ---------------- attention scores via exp-factorized tanh ----------------
__global__ __launch_bounds__(256) void k_feat(const float* __restrict__ Eh,
                                              const unsigned short* __restrict__ Ex,
                                              const float* __restrict__ attw_w,
                                              float* __restrict__ s_all) {
  __shared__ float EhL[TT][512];
  __shared__ float wL[512];
  const int tid = threadIdx.x;
  const int tg = blockIdx.x >> 7, b = blockIdx.x & 127;
  const int t0 = tg * TT;
  for (int i = tid * 4; i < TT * 512; i += 1024) {
    int t = i >> 9, c = i & 511;
    *(float4*)&EhL[t][c] = *(const float4*)&Eh[((size_t)(t0 + t) * 128 + b) * 512 + c];
  }
  if (tid < 128) *(float4*)&wL[tid * 4] = *(const float4*)&attw_w[tid * 4];
  __syncthreads();
  const int p = tid;
  const unsigned short* xp = Ex + (size_t)b * 512 * 256 + p;
  float acc[TT];
#pragma unroll
  for (int t = 0; t < TT; t++) acc[t] = 0.f;
  for (int c0 = 0; c0 < 512; c0 += 4) {
    float ex0 = bf2f(xp[(size_t)(c0 + 0) * 256]);
    float ex1 = bf2f(xp[(size_t)(c0 + 1) * 256]);
    float ex2 = bf2f(xp[(size_t)(c0 + 2) * 256]);
    float ex3 = bf2f(xp[(size_t)(c0 + 3) * 256]);
    float4 wv = *(const float4*)&wL[c0];
#pragma unroll
    for (int t = 0; t < TT; t++) {
      float4 eh = *(const float4*)&EhL[t][c0];
      acc[t] = __builtin_fmaf(wv.x, rcp_f(__builtin_fmaf(ex0, eh.x, 1.f)), acc[t]);
      acc[t] = __builtin_fmaf(wv.y, rcp_f(__builtin_fmaf(ex1, eh.y, 1.f)), acc[t]);
      acc[t] = __builtin_fmaf(wv.z, rcp_f(__builtin_fmaf(ex2, eh.z, 1.f)), acc[t]);
      acc[t] = __builtin_fmaf(wv.w, rcp_f(__builtin_fmaf(ex3, eh.w, 1.f)), acc[t]);
    }
  }
#pragma unroll
  for (int t = 0; t < TT; t++)
    s_all[((size_t)(t0 + t) * 128 + b) * 256 + p] = -2.f * acc[t];
}

// ---------------- softmax over p (per t,b) + att[t,b,d] = sum_p alpha * att_x_em[b,p,d] ----------------
__global__ __launch_bounds__(256) void k_att(const float* __restrict__ s_all,
                                             const float* __restrict__ atx,
                                             unsigned short* __restrict__ hatt) {
  __shared__ float sL[40][257];
  __shared__ float zinv[40];
  const int tid = threadIdx.x;
  const int b = blockIdx.x >> 1, dh = blockIdx.x & 1;
  for (int i = tid; i < 40 * 256; i += 256) {
    int t = i >> 8, p = i & 255;
    sL[t][p] = s_all[((size_t)t * 128 + b) * 256 + p];
  }
  __syncthreads();
  if (tid < 40) {
    int t = tid;
    float mx = -1e30f;
    for (int p = 0; p < 256; p++) mx = fmaxf(mx, sL[t][p]);
    float z = 0.f;
    for (int p = 0; p < 256; p++) { float e = __expf(sL[t][p] - mx); sL[t][p] = e; z += e; }
    zinv[t] = 1.f / z;
  }
  __syncthreads();
  float acc[40];
#pragma unroll
  for (int t = 0; t < 40; t++) acc[t] = 0.f;
  const int d = dh * 256 + tid;
  const float* ap = atx + (size_t)b * 256 * 512 + d;
  for (int p = 0; p < 256; p++) {
    float av = ap[(size_t)p * 512];
#pragma unroll
    for (int t = 0; t < 40; t++) acc[t] += sL[t][p] * av;
  }
#pragma unroll
  for (int t = 0; t < 40; t++) {
    float v = acc[t] * zinv[t];
    hatt[((size_t)t * 128 + b) * 1024 + 512 + d] = f2bf(v);
  }
}

// ---------------- in-place log_softmax over rows of 7000 in d_out ----------------
__global__ __launch_bounds__(256) void k_lsm(float* __restrict__ out) {
  __shared__ float buf[7000];
  __shared__ float red[256];
  const int tid = threadIdx.x;
  float* pr = out + (size_t)blockIdx.x * NCLS;
  for (int i = tid * 4; i < NCLS; i += 1024)
    *(float4*)&buf[i] = *(const float4*)&pr[i];
  __syncthreads();
  float mx = -1e30f;
  for (int i = tid; i < NCLS; i += 256) mx = fmaxf(mx, buf[i]);
  red[tid] = mx; __syncthreads();
  for (int s = 128; s > 0; s >>= 1) { if (tid < s) red[tid] = fmaxf(red[tid], red[tid + s]); __syncthreads(); }
  mx = red[0]; __syncthreads();
  float sum = 0.f;
  for (int i = tid; i < NCLS; i += 256) sum += __expf(buf[i] - mx);
  red[tid] = sum; __syncthreads();
  for (int s = 128; s > 0; s >>= 1) { if (tid < s) red[tid] += red[tid + s]; __syncthreads(); }
  float lse = mx + __logf(red[0]);
  for (int i = tid * 4; i < NCLS; i += 1024) {
    float4 v = *(const float4*)&buf[i];
    v.x -= lse; v.y -= lse; v.z -= lse; v.w -= lse;
    *(float4*)&pr[i] = v;
  }
}

extern "C" void kernel_launch(void* const* d_in, const int* in_sizes, int n_in,
                              void* d_out, int out_size, void* d_ws, size_t ws_size,
                              hipStream_t stream) {
  const float* hidden_en = (const float*)d_in[0];
  const float* x_em      = (const float*)d_in[1];
  const float* att_x     = (const float*)d_in[2];
  const int*   target    = (const int*)d_in[3];
  const float* embed_w   = (const float*)d_in[6];
  const float* W_ih      = (const float*)d_in[7];
  const float* W_hh      = (const float*)d_in[8];
  const float* b_ih      = (const float*)d_in[9];
  const float* b_hh      = (const float*)d_in[10];
  const float* hem_w     = (const float*)d_in[11];
  const float* hem_b     = (const float*)d_in[12];
  const float* attw_w    = (const float*)d_in[13];
  const float* lin_w     = (const float*)d_in[15];
  const float* lin_b     = (const float*)d_in[16];
  float* out = (float*)d_out;
  (void)in_sizes; (void)n_in; (void)out_size; (void)ws_size;

  char* w = (char*)d_ws;
  size_t off = 0;
  auto alloc = [&](size_t bytes) { char* p = w + off; off = (off + bytes + 255) & ~(size_t)255; return p; };
  unsigned short* xts  = (unsigned short*)alloc((size_t)MROWS * 512 * 2);
  unsigned short* wihp = (unsigned short*)alloc((size_t)2048 * 512 * 2);  // W_ih bf16, R3-perm rows
  unsigned short* whhp = (unsigned short*)alloc((size_t)2048 * 512 * 2);  // W_hh bf16, R3-perm rows
  unsigned short* xg   = (unsigned short*)alloc((size_t)MROWS * 2048 * 2); // perm cols, biases baked
  unsigned short* hemw = (unsigned short*)alloc((size_t)512 * 512 * 2);
  unsigned short* linw = (unsigned short*)alloc((size_t)NPAD * 1024 * 2);
  unsigned short* xem  = (unsigned short*)alloc((size_t)128 * 512 * 256 * 2);  // Ex = exp(2*x_em)
  unsigned short* hatt = (unsigned short*)alloc((size_t)MROWS * 1024 * 2);
  unsigned short* h0   = (unsigned short*)alloc((size_t)128 * 512 * 2);
  unsigned short* h1   = (unsigned short*)alloc((size_t)128 * 512 * 2);
  float* bsum    = (float*)alloc((size_t)2048 * 4);          // b_ih + b_hh, permuted
  float* eh_all  = (float*)alloc((size_t)MROWS * 512 * 4);   // Eh = exp(2*hem)
  float* s_all   = (float*)alloc((size_t)MROWS * 256 * 4);
  int*   cnt     = (int*)alloc(256);                         // scan barrier counter

  // --- all preprocessing in ONE launch (cnt zeroed inside, stream-ordered) ---
  k_pre<<<28288, 256, 0, stream>>>(W_ih, W_hh, wihp, whhp, b_ih, b_hh, bsum,
                                   hem_w, hemw, x_em, xem, lin_w, linw,
                                   hidden_en, embed_w, target, xts, cnt);
  // xg_all = xts @ W_ih_perm^T + (b_ih + b_hh)  (bf16 out, permuted cols)
  k_gemm<0><<<dim3(40, 16), 256, 0, stream>>>(xts, 512, wihp, 512, bsum, xg, 2048, 512);

  // --- fused sequential LSTM scan: ONE persistent cooperative launch ---
  {
    int t0 = 0, t1 = LSEQ;
    void* args[] = { (void*)&h0, (void*)&h1, (void*)&xg, (void*)&whhp, (void*)&hatt,
                     (void*)&cnt, (void*)&t0, (void*)&t1 };
    hipError_t ce = hipLaunchCooperativeKernel(k_scan5, dim3(SBLK), dim3(1024), args, 0u, stream);
    if (ce != hipSuccess) {
      // fallback: 40 single-step launches of the SAME kernel (barrier skipped)
      for (int t = 0; t < LSEQ; t++)
        k_scan5<<<SBLK, 1024, 0, stream>>>(h0, h1, xg, whhp, hatt, cnt, t, t + 1);
    }
  }

  // --- batched attention over all 40 steps ---
  // Eh = exp(2*(h@hem_w^T + hem_b)) fused into GEMM epilogue (MODE 3)
  k_gemm<3><<<dim3(40, 4), 256, 0, stream>>>(hatt, 1024, hemw, 512, hem_b, eh_all, 512, 512);
  k_feat<<<512, 256, 0, stream>>>(eh_all, xem, attw_w, s_all);
  k_att<<<256, 256, 0, stream>>>(s_all, att_x, hatt);

  // --- logits + log_softmax ---
  k_gemm<2><<<dim3(40, 55), 256, 0, stream>>>(hatt, 1024, linw, 1024, lin_b, out, NCLS, 1024);
  k_lsm<<<MROWS, 256, 0, stream>>>(out);
}